// Round 1
// 773.423 us; speedup vs baseline: 1.1932x; 1.1932x over previous
//
#include <hip/hip_runtime.h>
#include <cstdint>
#include <cstddef>

// Problem constants (B,H,W,C)=(4,128,128,512), HID=768, HEADS=8, BS=8
#define Bb     4
#define Cc     512
#define HID    768
#define HEADS  8
#define NBT    256
#define BS2    64
#define HD     96
#define HWTOK  16384
#define MTOK   65536
#define N3     2304

typedef __attribute__((ext_vector_type(8))) short frag16;
typedef __attribute__((ext_vector_type(4))) float f32x4;

__device__ __forceinline__ float b2f(unsigned short u) {
    union { unsigned int i; float f; } x; x.i = ((unsigned int)u) << 16; return x.f;
}
__device__ __forceinline__ unsigned short f2b(float f) {
    union { float f; unsigned int i; } x; x.f = f;
    unsigned int r = x.i + 0x7fffu + ((x.i >> 16) & 1u);   // RNE
    return (unsigned short)(r >> 16);
}
union cvt8 { uint4 u; unsigned short s[8]; };

__device__ __forceinline__ void gl2lds16(const void* g, void* l) {
    __builtin_amdgcn_global_load_lds(
        (const __attribute__((address_space(1))) unsigned int*)g,
        (__attribute__((address_space(3))) unsigned int*)l, 16, 0, 0);
}

// overflow-safe fast tanh: tanh(x) = sign(x) * (1-e)/(1+e), e = exp(-2|x|)
__device__ __forceinline__ float fast_tanh(float x) {
    float a = __builtin_fabsf(x);
    float t = __expf(-2.0f * a);
    float r = (1.0f - t) / (1.0f + t);
    return __builtin_copysignf(r, x);
}

// ---------------- kernel 0: weight transpose fp32 -> bf16 (B^T) ------------
__global__ __launch_bounds__(256) void k_transpose(
    const float* __restrict__ w, unsigned short* __restrict__ wt,
    int K, int N) {
    int e = blockIdx.x * 256 + threadIdx.x;
    if (e < K * N) {
        int k = e / N, n = e - k * N;
        wt[(size_t)n * K + k] = f2b(w[e]);
    }
}

// ---------------- kernel 0b: gather + fp32->bf16 convert of x --------------
__global__ __launch_bounds__(256) void k_gather(
    const float* __restrict__ x, const int* __restrict__ idx,
    unsigned short* __restrict__ xg) {          // (MTOK, 512) bf16
    int gid = blockIdx.x * 256 + threadIdx.x;   // MTOK*64 chunks of 8
    int t = gid >> 6, col = (gid & 63) * 8;
    int bb = t >> 14, hw = t & 16383;
    const float* src = x + ((size_t)bb * HWTOK + idx[hw]) * Cc + col;
    float4 f0 = *(const float4*)src, f1 = *(const float4*)(src + 4);
    cvt8 c;
    c.s[0] = f2b(f0.x); c.s[1] = f2b(f0.y); c.s[2] = f2b(f0.z); c.s[3] = f2b(f0.w);
    c.s[4] = f2b(f1.x); c.s[5] = f2b(f1.y); c.s[6] = f2b(f1.z); c.s[7] = f2b(f1.w);
    *(uint4*)(xg + (size_t)t * Cc + col) = c.u;
}

// ---------------- kernel 1: in_proj + GLU (prefetch dbuf + frag-major LDS) -
// 128m x (64n x 3 slices) tile. LDS laid out as 1KB "fragment subtiles":
// subtile s holds 16 rows x 32 k of one operand, element (r,k) at byte
// r*16 + (k/8)*256 + (k%8)*2, so the DMA's linear lane*16 dest IS the
// fragment order and every ds_read_b128 is base + lane*16 (conflict-free).
__global__ __launch_bounds__(256) void k_inproj(
    const unsigned short* __restrict__ xg,     // (MTOK, 512) bf16
    const unsigned short* __restrict__ winT,   // (2304, 512) bf16
    const float* __restrict__ b_in,            // (2304) fp32
    unsigned short* __restrict__ y_img,        // (MTOK, HID) bf16
    unsigned short* __restrict__ vt_blk) {     // (HEADS,B,NBT,BS2,HD) bf16
    // double-buffered: A 8 subtiles (4096 sh) + B 12 subtiles (6144 sh)
    __shared__ alignas(16) unsigned short smem[2][4096 + 6144];   // 40 KB
    const int tid = threadIdx.x;
    const int wv = tid >> 6, lane = tid & 63;
    const int wm = wv >> 1, wn = wv & 1;
    const int fr = lane & 15, q = lane >> 4;
    const int n0 = blockIdx.x * 64;     // per-slice col base [0,768)
    const int m0 = blockIdx.y * 128;

    // 20 DMA chunks of 1024B (A:0-7, B:8-19), 5 per wave.
    // fragment-order source: lane loads (row = sub*16 + fr, k = q*8..q*8+7)
    const unsigned short* gsrc[5];
    int loff[5];
    #pragma unroll
    for (int ci = 0; ci < 5; ci++) {
        int c = wv * 5 + ci;
        if (c < 8) {
            gsrc[ci] = xg + (size_t)(m0 + c * 16 + fr) * Cc + q * 8;
            loff[ci] = c * 512;
        } else {
            int cb = c - 8, sl = cb >> 2;
            gsrc[ci] = winT + (size_t)(sl * HID + n0 + (cb & 3) * 16 + fr) * Cc + q * 8;
            loff[ci] = 4096 + cb * 512;
        }
    }

    f32x4 acc[3][2][4];
    #pragma unroll
    for (int sl = 0; sl < 3; sl++)
        #pragma unroll
        for (int nt = 0; nt < 2; nt++)
            #pragma unroll
            for (int mt = 0; mt < 4; mt++) acc[sl][nt][mt] = (f32x4){0.f,0.f,0.f,0.f};

    // prologue: stage tile 0 into buffer 0
    #pragma unroll
    for (int ci = 0; ci < 5; ci++)
        gl2lds16(gsrc[ci], &smem[0][loff[ci]]);
    __syncthreads();

    // T3-minimal pipeline: stage tile kt while computing tile kt-1;
    // one vmcnt(0)+barrier (inside __syncthreads) per tile.
    #pragma unroll 2
    for (int kt = 1; kt <= 16; kt++) {
        if (kt < 16) {
            #pragma unroll
            for (int ci = 0; ci < 5; ci++)
                gl2lds16(gsrc[ci] + kt * 32, &smem[kt & 1][loff[ci]]);
        }
        const unsigned short* sa = smem[(kt - 1) & 1];
        frag16 af[4];
        #pragma unroll
        for (int mt = 0; mt < 4; mt++)
            af[mt] = *(const frag16*)(sa + (wm * 4 + mt) * 512 + lane * 8);
        #pragma unroll
        for (int sl = 0; sl < 3; sl++) {
            #pragma unroll
            for (int nt = 0; nt < 2; nt++) {
                frag16 bf = *(const frag16*)(sa + 4096 +
                                             (sl * 4 + wn * 2 + nt) * 512 + lane * 8);
                #pragma unroll
                for (int mt = 0; mt < 4; mt++)
                    acc[sl][nt][mt] = __builtin_amdgcn_mfma_f32_16x16x32_bf16(
                        af[mt], bf, acc[sl][nt][mt], 0, 0, 0);
            }
        }
        __syncthreads();
    }

    // epilogue: GLU + layout writes
    #pragma unroll
    for (int nt = 0; nt < 2; nt++) {
        const int j = n0 + wn * 32 + nt * 16 + fr;
        const float bs = b_in[j], bv = b_in[HID + j], by = b_in[2 * HID + j];
        const int h = j / HD, d = j - h * HD;
        #pragma unroll
        for (int mt = 0; mt < 4; mt++) {
            #pragma unroll
            for (int r = 0; r < 4; r++) {
                const int t = m0 + wm * 64 + mt * 16 + q * 4 + r;
                const int bb = t >> 14, hw = t & 16383;
                const float sv = acc[0][nt][mt][r] + bs;
                const float vv = acc[1][nt][mt][r] + bv;
                const float yv = acc[2][nt][mt][r] + by;
                y_img[(size_t)t * HID + j] = f2b(yv);
                const int hr = hw >> 7, wc = hw & 127;
                const int nblk = ((hr >> 3) << 4) | (wc >> 3);
                const int ii   = ((hr & 7) << 3) | (wc & 7);
                vt_blk[((((size_t)h * Bb + bb) * NBT + nblk) * BS2 + ii) * HD + d] =
                    f2b(vv * fast_tanh(sv));
            }
        }
    }
}

// ---------------- kernel 2: block attention (MFMA) + y multiply ------------
// av[i,d] = sum_j attn[g,i,j] * vt[g,j,d];  y_img <- av * y_img (in place)
__global__ __launch_bounds__(256) void k_attn(
    const float* __restrict__ attnw,            // (HEADS,B,NBT,64,64) fp32
    const unsigned short* __restrict__ vt_blk,  // (HEADS,B,NBT,64,96) bf16
    unsigned short* __restrict__ y_img) {       // (MTOK,HID) bf16, in/out
    __shared__ alignas(16) unsigned short Aat[64][72];   // attn bf16, padded
    __shared__ alignas(16) unsigned short VtT[96][72];   // vt transposed (B^T)
    const int tid = threadIdx.x;
    const int g = blockIdx.x;                   // (h*B + b)*NBT + n
    const int wv = tid >> 6, lane = tid & 63;
    const int fr = lane & 15, q = lane >> 4;
    const int wm = wv >> 1, wn = wv & 1;

    const float* asrc = attnw + (size_t)g * 4096;
    const unsigned short* vsrc = vt_blk + (size_t)g * 6144;
    #pragma unroll
    for (int r = 0; r < 2; r++) {               // attn: 512 chunks of 8 floats
        int v = tid + 256 * r;
        int i = v >> 3, jj = (v & 7) * 8;
        const float* ap = asrc + (size_t)v * 8;
        float4 f0 = *(const float4*)ap, f1 = *(const float4*)(ap + 4);
        cvt8 c;
        c.s[0]=f2b(f0.x); c.s[1]=f2b(f0.y); c.s[2]=f2b(f0.z); c.s[3]=f2b(f0.w);
        c.s[4]=f2b(f1.x); c.s[5]=f2b(f1.y); c.s[6]=f2b(f1.z); c.s[7]=f2b(f1.w);
        *(uint4*)(&Aat[i][jj]) = c.u;
    }
    #pragma unroll
    for (int r = 0; r < 3; r++) {               // vt: 768 uint4, transpose
        int v = tid + 256 * r;
        int j = v / 12, dq = v - j * 12;
        cvt8 c; c.u = ((const uint4*)vsrc)[v];
        #pragma unroll
        for (int e = 0; e < 8; e++) VtT[dq * 8 + e][j] = c.s[e];
    }
    __syncthreads();

    f32x4 acc[2][3];                            // [mt:i][ndt:d]
    #pragma unroll
    for (int mt = 0; mt < 2; mt++)
        #pragma unroll
        for (int nd = 0; nd < 3; nd++) acc[mt][nd] = (f32x4){0.f,0.f,0.f,0.f};
    #pragma unroll
    for (int kk = 0; kk < 2; kk++) {
        frag16 af[2];
        #pragma unroll
        for (int mt = 0; mt < 2; mt++)
            af[mt] = *(const frag16*)(&Aat[wm * 32 + mt * 16 + fr][kk * 32 + q * 8]);
        #pragma unroll
        for (int nd = 0; nd < 3; nd++) {
            frag16 bf = *(const frag16*)(&VtT[wn * 48 + nd * 16 + fr][kk * 32 + q * 8]);
            #pragma unroll
            for (int mt = 0; mt < 2; mt++)
                acc[mt][nd] = __builtin_amdgcn_mfma_f32_16x16x32_bf16(
                    af[mt], bf, acc[mt][nd], 0, 0, 0);
        }
    }

    const int h = g >> 10, b = (g >> 8) & 3, n = g & 255;
    #pragma unroll
    for (int nd = 0; nd < 3; nd++) {
        const int d = wn * 48 + nd * 16 + fr;
        #pragma unroll
        for (int mt = 0; mt < 2; mt++) {
            #pragma unroll
            for (int r = 0; r < 4; r++) {
                const int i = wm * 32 + mt * 16 + q * 4 + r;
                const int hr = ((n >> 4) << 3) | (i >> 3);
                const int wc = ((n & 15) << 3) | (i & 7);
                const size_t t = ((size_t)b << 14) + (size_t)hr * 128 + wc;
                const size_t off = t * HID + (size_t)h * HD + d;
                y_img[off] = f2b(acc[mt][nd][r] * b2f(y_img[off]));
            }
        }
    }
}

// ---------------- kernel 3: out_proj + bias + scatter (prefetch dbuf) ------
__global__ __launch_bounds__(256) void k_outproj(
    const unsigned short* __restrict__ avy,     // (MTOK,HID) bf16 (=y_img)
    const unsigned short* __restrict__ woutT,   // (512, 768) bf16
    const float* __restrict__ b_out,            // (512) fp32
    const int* __restrict__ idx,
    float* __restrict__ out) {                  // (B,HW,C) fp32
    // double-buffered: A 8 subtiles + B 8 subtiles, fragment-major
    __shared__ alignas(16) unsigned short smem[2][8192];   // 32 KB
    const int tid = threadIdx.x;
    const int wv = tid >> 6, lane = tid & 63;
    const int wm = wv >> 1, wn = wv & 1;
    const int fr = lane & 15, q = lane >> 4;
    const int c0 = blockIdx.x * 128;
    const int m0 = blockIdx.y * 128;

    const unsigned short* gsrc[4];
    int loff[4];
    #pragma unroll
    for (int ci = 0; ci < 4; ci++) {
        int c = wv * 4 + ci;
        if (c < 8) {
            gsrc[ci] = avy + (size_t)(m0 + c * 16 + fr) * HID + q * 8;
            loff[ci] = c * 512;
        } else {
            int cb = c - 8;
            gsrc[ci] = woutT + (size_t)(c0 + cb * 16 + fr) * HID + q * 8;
            loff[ci] = 4096 + cb * 512;
        }
    }

    f32x4 acc[4][4];
    #pragma unroll
    for (int nt = 0; nt < 4; nt++)
        #pragma unroll
        for (int mt = 0; mt < 4; mt++) acc[nt][mt] = (f32x4){0.f,0.f,0.f,0.f};

    #pragma unroll
    for (int ci = 0; ci < 4; ci++)
        gl2lds16(gsrc[ci], &smem[0][loff[ci]]);
    __syncthreads();

    #pragma unroll 2
    for (int kt = 1; kt <= 24; kt++) {
        if (kt < 24) {
            #pragma unroll
            for (int ci = 0; ci < 4; ci++)
                gl2lds16(gsrc[ci] + kt * 32, &smem[kt & 1][loff[ci]]);
        }
        const unsigned short* sa = smem[(kt - 1) & 1];
        frag16 af[4];
        #pragma unroll
        for (int mt = 0; mt < 4; mt++)
            af[mt] = *(const frag16*)(sa + (wm * 4 + mt) * 512 + lane * 8);
        #pragma unroll
        for (int nt = 0; nt < 4; nt++) {
            frag16 bf = *(const frag16*)(sa + 4096 + (wn * 4 + nt) * 512 + lane * 8);
            #pragma unroll
            for (int mt = 0; mt < 4; mt++)
                acc[nt][mt] = __builtin_amdgcn_mfma_f32_16x16x32_bf16(
                    af[mt], bf, acc[nt][mt], 0, 0, 0);
        }
        __syncthreads();
    }

    #pragma unroll
    for (int nt = 0; nt < 4; nt++) {
        const int c = c0 + wn * 64 + nt * 16 + fr;
        const float bo = b_out[c];
        #pragma unroll
        for (int mt = 0; mt < 4; mt++) {
            #pragma unroll
            for (int r = 0; r < 4; r++) {
                const int t = m0 + wm * 64 + mt * 16 + q * 4 + r;
                const int bb = t >> 14, hw = t & 16383;
                const int dst = idx[hw];
                out[((size_t)bb * HWTOK + dst) * Cc + c] = acc[nt][mt][r] + bo;
            }
        }
    }
}

extern "C" void kernel_launch(void* const* d_in, const int* in_sizes, int n_in,
                              void* d_out, int out_size, void* d_ws, size_t ws_size,
                              hipStream_t stream) {
    const float* x     = (const float*)d_in[0];
    const float* attnw = (const float*)d_in[1];
    const float* W_in  = (const float*)d_in[2];
    const float* b_in  = (const float*)d_in[3];
    const float* W_out = (const float*)d_in[4];
    const float* b_out = (const float*)d_in[5];
    const int*   idx   = (const int*)d_in[6];
    float*       out   = (float*)d_out;

    // workspace carve-up (~204.5 MB)
    char* p = (char*)d_ws;
    unsigned short* winT  = (unsigned short*)p; p += (size_t)N3 * Cc * 2;
    unsigned short* woutT = (unsigned short*)p; p += (size_t)Cc * HID * 2;
    unsigned short* vt    = (unsigned short*)p; p += (size_t)HEADS * Bb * NBT * BS2 * HD * 2;
    unsigned short* y_img = (unsigned short*)p; p += (size_t)MTOK * HID * 2;
    // xg (67 MB bf16) lives in d_out — dead until k_outproj writes it
    unsigned short* xg = (unsigned short*)d_out;

    k_transpose<<<(N3 * Cc + 255) / 256, 256, 0, stream>>>(W_in, winT, Cc, N3);
    k_transpose<<<(HID * Cc + 255) / 256, 256, 0, stream>>>(W_out, woutT, HID, Cc);
    k_gather<<<MTOK * 64 / 256, 256, 0, stream>>>(x, idx, xg);

    dim3 g1(HID / 64, MTOK / 128);  // (12, 512)
    k_inproj<<<g1, 256, 0, stream>>>(xg, winT, b_in, y_img, vt);

    k_attn<<<HEADS * Bb * NBT, 256, 0, stream>>>(attnw, vt, y_img);

    dim3 g3(Cc / 128, MTOK / 128);  // (4, 512)
    k_outproj<<<g3, 256, 0, stream>>>(y_img, woutT, b_out, idx, out);
}

// Round 2
// 754.357 us; speedup vs baseline: 1.2234x; 1.0253x over previous
//
#include <hip/hip_runtime.h>
#include <cstdint>
#include <cstddef>

// Problem constants (B,H,W,C)=(4,128,128,512), HID=768, HEADS=8, BS=8
#define Bb     4
#define Cc     512
#define HID    768
#define HEADS  8
#define NBT    256
#define BS2    64
#define HD     96
#define HWTOK  16384
#define MTOK   65536
#define N3     2304

typedef __attribute__((ext_vector_type(8))) short frag16;
typedef __attribute__((ext_vector_type(4))) float f32x4;

__device__ __forceinline__ float b2f(unsigned short u) {
    union { unsigned int i; float f; } x; x.i = ((unsigned int)u) << 16; return x.f;
}
__device__ __forceinline__ unsigned short f2b(float f) {
    union { float f; unsigned int i; } x; x.f = f;
    unsigned int r = x.i + 0x7fffu + ((x.i >> 16) & 1u);   // RNE
    return (unsigned short)(r >> 16);
}
union cvt8 { uint4 u; unsigned short s[8]; };

__device__ __forceinline__ void gl2lds16(const void* g, void* l) {
    __builtin_amdgcn_global_load_lds(
        (const __attribute__((address_space(1))) unsigned int*)g,
        (__attribute__((address_space(3))) unsigned int*)l, 16, 0, 0);
}

// overflow-safe fast tanh: tanh(x) = sign(x) * (1-e)/(1+e), e = exp(-2|x|)
__device__ __forceinline__ float fast_tanh(float x) {
    float a = __builtin_fabsf(x);
    float t = __expf(-2.0f * a);
    float r = (1.0f - t) / (1.0f + t);
    return __builtin_copysignf(r, x);
}

// ---------------- kernel 0: weight transpose fp32 -> bf16 (B^T) ------------
__global__ __launch_bounds__(256) void k_transpose(
    const float* __restrict__ w, unsigned short* __restrict__ wt,
    int K, int N) {
    int e = blockIdx.x * 256 + threadIdx.x;
    if (e < K * N) {
        int k = e / N, n = e - k * N;
        wt[(size_t)n * K + k] = f2b(w[e]);
    }
}

// ---------------- kernel 0b: gather + fp32->bf16 convert of x --------------
__global__ __launch_bounds__(256) void k_gather(
    const float* __restrict__ x, const int* __restrict__ idx,
    unsigned short* __restrict__ xg) {          // (MTOK, 512) bf16
    int gid = blockIdx.x * 256 + threadIdx.x;   // MTOK*64 chunks of 8
    int t = gid >> 6, col = (gid & 63) * 8;
    int bb = t >> 14, hw = t & 16383;
    const float* src = x + ((size_t)bb * HWTOK + idx[hw]) * Cc + col;
    float4 f0 = *(const float4*)src, f1 = *(const float4*)(src + 4);
    cvt8 c;
    c.s[0] = f2b(f0.x); c.s[1] = f2b(f0.y); c.s[2] = f2b(f0.z); c.s[3] = f2b(f0.w);
    c.s[4] = f2b(f1.x); c.s[5] = f2b(f1.y); c.s[6] = f2b(f1.z); c.s[7] = f2b(f1.w);
    *(uint4*)(xg + (size_t)t * Cc + col) = c.u;
}

// ---------------- kernel 1: in_proj + GLU --------------------------------
// 128m x (64n x 3 slices) tile, fragment-major LDS (conflict-free),
// 4-buffer prefetch-distance-2 pipeline with counted vmcnt (T3/T4),
// setprio around MFMA (T5), XCD-grouped block swizzle (T1).
__global__ __launch_bounds__(256) void k_inproj(
    const unsigned short* __restrict__ xg,     // (MTOK, 512) bf16
    const unsigned short* __restrict__ winT,   // (2304, 512) bf16
    const float* __restrict__ b_in,            // (2304) fp32
    unsigned short* __restrict__ y_img,        // (MTOK, HID) bf16
    unsigned short* __restrict__ vt_blk) {     // (HEADS,B,NBT,BS2,HD) bf16
    // 4 buffers x (A 8 subtiles + B 12 subtiles) x 1KB = 80 KB
    __shared__ alignas(16) unsigned short smem[4][10240];
    const int tid = threadIdx.x;
    const int wv = tid >> 6, lane = tid & 63;
    const int wm = wv >> 1, wn = wv & 1;
    const int fr = lane & 15, q = lane >> 4;

    // XCD swizzle: all 12 column-blocks of one 128-row panel -> same XCD
    const int fb = blockIdx.x + 12 * blockIdx.y;        // 0..6143 = 8*768
    const int sb = (fb & 7) * 768 + (fb >> 3);
    const int n0 = (sb % 12) * 64;      // per-slice col base [0,768)
    const int m0 = (sb / 12) * 128;

    // 20 DMA chunks of 1024B (A:0-7, B:8-19), 5 per wave.
    // fragment-order source: lane loads (row = sub*16 + fr, k = q*8..q*8+7)
    const unsigned short* gsrc[5];
    int loff[5];
    #pragma unroll
    for (int ci = 0; ci < 5; ci++) {
        int c = wv * 5 + ci;
        if (c < 8) {
            gsrc[ci] = xg + (size_t)(m0 + c * 16 + fr) * Cc + q * 8;
            loff[ci] = c * 512;
        } else {
            int cb = c - 8, sl = cb >> 2;
            gsrc[ci] = winT + (size_t)(sl * HID + n0 + (cb & 3) * 16 + fr) * Cc + q * 8;
            loff[ci] = 4096 + cb * 512;
        }
    }

    f32x4 acc[3][2][4];
    #pragma unroll
    for (int sl = 0; sl < 3; sl++)
        #pragma unroll
        for (int nt = 0; nt < 2; nt++)
            #pragma unroll
            for (int mt = 0; mt < 4; mt++) acc[sl][nt][mt] = (f32x4){0.f,0.f,0.f,0.f};

    // prologue: tiles 0,1 in flight
    #pragma unroll
    for (int ci = 0; ci < 5; ci++) gl2lds16(gsrc[ci], &smem[0][loff[ci]]);
    #pragma unroll
    for (int ci = 0; ci < 5; ci++) gl2lds16(gsrc[ci] + 32, &smem[1][loff[ci]]);

    // main pipeline: issue t+2, wait own tile t (vmcnt(10) = 2 tiles in
    // flight), barrier, compute t.  Never drains vmcnt to 0 mid-loop.
    #pragma unroll
    for (int t = 0; t < 16; t++) {
        if (t < 14) {
            const int bi = (t + 2) & 3;
            #pragma unroll
            for (int ci = 0; ci < 5; ci++)
                gl2lds16(gsrc[ci] + (t + 2) * 32, &smem[bi][loff[ci]]);
            asm volatile("s_waitcnt vmcnt(10)" ::: "memory");
        } else if (t == 14) {
            asm volatile("s_waitcnt vmcnt(5)" ::: "memory");
        } else {
            asm volatile("s_waitcnt vmcnt(0)" ::: "memory");
        }
        __builtin_amdgcn_s_barrier();
        const unsigned short* sa = smem[t & 3];
        frag16 af[4];
        #pragma unroll
        for (int mt = 0; mt < 4; mt++)
            af[mt] = *(const frag16*)(sa + (wm * 4 + mt) * 512 + lane * 8);
        __builtin_amdgcn_s_setprio(1);
        #pragma unroll
        for (int sl = 0; sl < 3; sl++) {
            #pragma unroll
            for (int nt = 0; nt < 2; nt++) {
                frag16 bf = *(const frag16*)(sa + 4096 +
                                             (sl * 4 + wn * 2 + nt) * 512 + lane * 8);
                #pragma unroll
                for (int mt = 0; mt < 4; mt++)
                    acc[sl][nt][mt] = __builtin_amdgcn_mfma_f32_16x16x32_bf16(
                        af[mt], bf, acc[sl][nt][mt], 0, 0, 0);
            }
        }
        __builtin_amdgcn_s_setprio(0);
    }

    // epilogue: GLU + layout writes
    #pragma unroll
    for (int nt = 0; nt < 2; nt++) {
        const int j = n0 + wn * 32 + nt * 16 + fr;
        const float bs = b_in[j], bv = b_in[HID + j], by = b_in[2 * HID + j];
        const int h = j / HD, d = j - h * HD;
        #pragma unroll
        for (int mt = 0; mt < 4; mt++) {
            #pragma unroll
            for (int r = 0; r < 4; r++) {
                const int t = m0 + wm * 64 + mt * 16 + q * 4 + r;
                const int bb = t >> 14, hw = t & 16383;
                const float sv = acc[0][nt][mt][r] + bs;
                const float vv = acc[1][nt][mt][r] + bv;
                const float yv = acc[2][nt][mt][r] + by;
                y_img[(size_t)t * HID + j] = f2b(yv);
                const int hr = hw >> 7, wc = hw & 127;
                const int nblk = ((hr >> 3) << 4) | (wc >> 3);
                const int ii   = ((hr & 7) << 3) | (wc & 7);
                vt_blk[((((size_t)h * Bb + bb) * NBT + nblk) * BS2 + ii) * HD + d] =
                    f2b(vv * fast_tanh(sv));
            }
        }
    }
}

// ---------------- kernel 2: block attention (MFMA) + y multiply ------------
// av[i,d] = sum_j attn[g,i,j] * vt[g,j,d];  y_img <- av * y_img (in place)
__global__ __launch_bounds__(256) void k_attn(
    const float* __restrict__ attnw,            // (HEADS,B,NBT,64,64) fp32
    const unsigned short* __restrict__ vt_blk,  // (HEADS,B,NBT,64,96) bf16
    unsigned short* __restrict__ y_img) {       // (MTOK,HID) bf16, in/out
    __shared__ alignas(16) unsigned short Aat[64][72];   // attn bf16, padded
    __shared__ alignas(16) unsigned short VtT[96][72];   // vt transposed (B^T)
    const int tid = threadIdx.x;
    const int g = blockIdx.x;                   // (h*B + b)*NBT + n
    const int wv = tid >> 6, lane = tid & 63;
    const int fr = lane & 15, q = lane >> 4;
    const int wm = wv >> 1, wn = wv & 1;

    const float* asrc = attnw + (size_t)g * 4096;
    const unsigned short* vsrc = vt_blk + (size_t)g * 6144;
    #pragma unroll
    for (int r = 0; r < 2; r++) {               // attn: 512 chunks of 8 floats
        int v = tid + 256 * r;
        int i = v >> 3, jj = (v & 7) * 8;
        const float* ap = asrc + (size_t)v * 8;
        float4 f0 = *(const float4*)ap, f1 = *(const float4*)(ap + 4);
        cvt8 c;
        c.s[0]=f2b(f0.x); c.s[1]=f2b(f0.y); c.s[2]=f2b(f0.z); c.s[3]=f2b(f0.w);
        c.s[4]=f2b(f1.x); c.s[5]=f2b(f1.y); c.s[6]=f2b(f1.z); c.s[7]=f2b(f1.w);
        *(uint4*)(&Aat[i][jj]) = c.u;
    }
    #pragma unroll
    for (int r = 0; r < 3; r++) {               // vt: 768 uint4, transpose
        int v = tid + 256 * r;
        int j = v / 12, dq = v - j * 12;
        cvt8 c; c.u = ((const uint4*)vsrc)[v];
        #pragma unroll
        for (int e = 0; e < 8; e++) VtT[dq * 8 + e][j] = c.s[e];
    }
    __syncthreads();

    f32x4 acc[2][3];                            // [mt:i][ndt:d]
    #pragma unroll
    for (int mt = 0; mt < 2; mt++)
        #pragma unroll
        for (int nd = 0; nd < 3; nd++) acc[mt][nd] = (f32x4){0.f,0.f,0.f,0.f};
    #pragma unroll
    for (int kk = 0; kk < 2; kk++) {
        frag16 af[2];
        #pragma unroll
        for (int mt = 0; mt < 2; mt++)
            af[mt] = *(const frag16*)(&Aat[wm * 32 + mt * 16 + fr][kk * 32 + q * 8]);
        #pragma unroll
        for (int nd = 0; nd < 3; nd++) {
            frag16 bf = *(const frag16*)(&VtT[wn * 48 + nd * 16 + fr][kk * 32 + q * 8]);
            #pragma unroll
            for (int mt = 0; mt < 2; mt++)
                acc[mt][nd] = __builtin_amdgcn_mfma_f32_16x16x32_bf16(
                    af[mt], bf, acc[mt][nd], 0, 0, 0);
        }
    }

    const int h = g >> 10, b = (g >> 8) & 3, n = g & 255;
    #pragma unroll
    for (int nd = 0; nd < 3; nd++) {
        const int d = wn * 48 + nd * 16 + fr;
        #pragma unroll
        for (int mt = 0; mt < 2; mt++) {
            #pragma unroll
            for (int r = 0; r < 4; r++) {
                const int i = wm * 32 + mt * 16 + q * 4 + r;
                const int hr = ((n >> 4) << 3) | (i >> 3);
                const int wc = ((n & 15) << 3) | (i & 7);
                const size_t t = ((size_t)b << 14) + (size_t)hr * 128 + wc;
                const size_t off = t * HID + (size_t)h * HD + d;
                y_img[off] = f2b(acc[mt][nd][r] * b2f(y_img[off]));
            }
        }
    }
}

// ---------------- kernel 3: out_proj + bias + scatter ----------------------
// Same 4-buffer counted-vmcnt pipeline as k_inproj.
__global__ __launch_bounds__(256) void k_outproj(
    const unsigned short* __restrict__ avy,     // (MTOK,HID) bf16 (=y_img)
    const unsigned short* __restrict__ woutT,   // (512, 768) bf16
    const float* __restrict__ b_out,            // (512) fp32
    const int* __restrict__ idx,
    float* __restrict__ out) {                  // (B,HW,C) fp32
    // 4 buffers x (A 8 + B 8 subtiles) x 1KB = 64 KB
    __shared__ alignas(16) unsigned short smem[4][8192];
    const int tid = threadIdx.x;
    const int wv = tid >> 6, lane = tid & 63;
    const int wm = wv >> 1, wn = wv & 1;
    const int fr = lane & 15, q = lane >> 4;

    const int fb = blockIdx.x + 4 * blockIdx.y;         // 0..2047 = 8*256
    const int sb = (fb & 7) * 256 + (fb >> 3);
    const int c0 = (sb % 4) * 128;
    const int m0 = (sb / 4) * 128;

    const unsigned short* gsrc[4];
    int loff[4];
    #pragma unroll
    for (int ci = 0; ci < 4; ci++) {
        int c = wv * 4 + ci;
        if (c < 8) {
            gsrc[ci] = avy + (size_t)(m0 + c * 16 + fr) * HID + q * 8;
            loff[ci] = c * 512;
        } else {
            int cb = c - 8;
            gsrc[ci] = woutT + (size_t)(c0 + cb * 16 + fr) * HID + q * 8;
            loff[ci] = 4096 + cb * 512;
        }
    }

    f32x4 acc[4][4];
    #pragma unroll
    for (int nt = 0; nt < 4; nt++)
        #pragma unroll
        for (int mt = 0; mt < 4; mt++) acc[nt][mt] = (f32x4){0.f,0.f,0.f,0.f};

    #pragma unroll
    for (int ci = 0; ci < 4; ci++) gl2lds16(gsrc[ci], &smem[0][loff[ci]]);
    #pragma unroll
    for (int ci = 0; ci < 4; ci++) gl2lds16(gsrc[ci] + 32, &smem[1][loff[ci]]);

    #pragma unroll
    for (int t = 0; t < 24; t++) {
        if (t < 22) {
            const int bi = (t + 2) & 3;
            #pragma unroll
            for (int ci = 0; ci < 4; ci++)
                gl2lds16(gsrc[ci] + (t + 2) * 32, &smem[bi][loff[ci]]);
            asm volatile("s_waitcnt vmcnt(8)" ::: "memory");
        } else if (t == 22) {
            asm volatile("s_waitcnt vmcnt(4)" ::: "memory");
        } else {
            asm volatile("s_waitcnt vmcnt(0)" ::: "memory");
        }
        __builtin_amdgcn_s_barrier();
        const unsigned short* sa = smem[t & 3];
        frag16 af[4];
        #pragma unroll
        for (int mt = 0; mt < 4; mt++)
            af[mt] = *(const frag16*)(sa + (wm * 4 + mt) * 512 + lane * 8);
        __builtin_amdgcn_s_setprio(1);
        #pragma unroll
        for (int nt = 0; nt < 4; nt++) {
            frag16 bf = *(const frag16*)(sa + 4096 + (wn * 4 + nt) * 512 + lane * 8);
            #pragma unroll
            for (int mt = 0; mt < 4; mt++)
                acc[nt][mt] = __builtin_amdgcn_mfma_f32_16x16x32_bf16(
                    af[mt], bf, acc[nt][mt], 0, 0, 0);
        }
        __builtin_amdgcn_s_setprio(0);
    }

    #pragma unroll
    for (int nt = 0; nt < 4; nt++) {
        const int c = c0 + wn * 64 + nt * 16 + fr;
        const float bo = b_out[c];
        #pragma unroll
        for (int mt = 0; mt < 4; mt++) {
            #pragma unroll
            for (int r = 0; r < 4; r++) {
                const int t = m0 + wm * 64 + mt * 16 + q * 4 + r;
                const int bb = t >> 14, hw = t & 16383;
                const int dst = idx[hw];
                out[((size_t)bb * HWTOK + dst) * Cc + c] = acc[nt][mt][r] + bo;
            }
        }
    }
}

extern "C" void kernel_launch(void* const* d_in, const int* in_sizes, int n_in,
                              void* d_out, int out_size, void* d_ws, size_t ws_size,
                              hipStream_t stream) {
    const float* x     = (const float*)d_in[0];
    const float* attnw = (const float*)d_in[1];
    const float* W_in  = (const float*)d_in[2];
    const float* b_in  = (const float*)d_in[3];
    const float* W_out = (const float*)d_in[4];
    const float* b_out = (const float*)d_in[5];
    const int*   idx   = (const int*)d_in[6];
    float*       out   = (float*)d_out;

    // workspace carve-up (~204.5 MB)
    char* p = (char*)d_ws;
    unsigned short* winT  = (unsigned short*)p; p += (size_t)N3 * Cc * 2;
    unsigned short* woutT = (unsigned short*)p; p += (size_t)Cc * HID * 2;
    unsigned short* vt    = (unsigned short*)p; p += (size_t)HEADS * Bb * NBT * BS2 * HD * 2;
    unsigned short* y_img = (unsigned short*)p; p += (size_t)MTOK * HID * 2;
    // xg (67 MB bf16) lives in d_out — dead until k_outproj writes it
    unsigned short* xg = (unsigned short*)d_out;

    k_transpose<<<(N3 * Cc + 255) / 256, 256, 0, stream>>>(W_in, winT, Cc, N3);
    k_transpose<<<(HID * Cc + 255) / 256, 256, 0, stream>>>(W_out, woutT, HID, Cc);
    k_gather<<<MTOK * 64 / 256, 256, 0, stream>>>(x, idx, xg);

    dim3 g1(HID / 64, MTOK / 128);  // (12, 512)
    k_inproj<<<g1, 256, 0, stream>>>(xg, winT, b_in, y_img, vt);

    k_attn<<<HEADS * Bb * NBT, 256, 0, stream>>>(attnw, vt, y_img);

    dim3 g3(Cc / 128, MTOK / 128);  // (4, 512)
    k_outproj<<<g3, 256, 0, stream>>>(y_img, woutT, b_out, idx, out);
}